// Round 3
// baseline (79.201 us; speedup 1.0000x reference)
//
#include <hip/hip_runtime.h>
#include <hip/hip_cooperative_groups.h>

namespace cg = cooperative_groups;

// ---------------------------------------------------------------------------
// ConvBlock: y = clip(BN(tr(conv3x3(x^2, Wconv))), -1, 1)
// Wconv[oc][c][di][dj] = weight[oc>>3][(c*9+3di+dj)>>3][(oc-(c*9+3di+dj))&7]
// GEMM form: A = Wconv (M=64 oc), B = im2col(x^2) (N=65536 px), K=576.
// bf16 MFMA 32x32x16, 3-pass hi/lo precision split.
// BN fused via cooperative grid.sync(): tr values stay in registers.
// ---------------------------------------------------------------------------

#define A_MORR 0.8578f
#define R_MORR 0.8578f
#define TR_C1 (A_MORR * A_MORR + R_MORR * R_MORR)
#define TR_C2 (-2.0f * A_MORR * R_MORR)
#define TR_C3 (1.0f + (A_MORR * R_MORR) * (A_MORR * R_MORR))
#define BN_EPS 1e-5f

#define NPIX 65536
#define X2_LO 26112          // byte offset of lo-precision x2 plane in LDS
#define SMEM_BYTES 52224

typedef __attribute__((ext_vector_type(8))) short bf16x8;
typedef __attribute__((ext_vector_type(16))) float f32x16;

__device__ __forceinline__ void bf16split(float s, unsigned short& h, unsigned short& l) {
    union { float f; unsigned u; } cv; cv.f = s;
    unsigned r = (cv.u + 0x7fffu + ((cv.u >> 16) & 1u)) & 0xffff0000u;
    h = (unsigned short)(r >> 16);
    union { unsigned u; float f; } hv; hv.u = r;
    float lo = s - hv.f;
    cv.f = lo;
    unsigned r2 = cv.u + 0x7fffu + ((cv.u >> 16) & 1u);
    l = (unsigned short)(r2 >> 16);
}

// ---------------------------------------------------------------------------
// Kernel A: build fragment-ready bf16 hi/lo weights + zero stats.
// Layout: wfrag[(off*4+ks)*2+mt][prec][lane][8ch] : 72 * 2048 B = 147456 B
// ---------------------------------------------------------------------------
__global__ __launch_bounds__(256) void prep_kernel(const float* __restrict__ w,
                                                   char* __restrict__ wfrag,
                                                   float* __restrict__ stats) {
    int gtid = blockIdx.x * 256 + threadIdx.x;
    if (gtid < 128) stats[gtid] = 0.0f;
    if (gtid < 36864) {
        int j    = gtid & 7;
        int lane = (gtid >> 3) & 63;
        int okm  = gtid >> 9;           // ((off*4+ks)*2+mt), 0..71
        int mt   = okm & 1;
        int ks   = (okm >> 1) & 3;
        int off  = okm >> 3;
        int oc   = mt * 32 + (lane & 31);
        int c    = ks * 16 + (lane >> 5) * 8 + j;
        int kg   = c * 9 + off;
        float val = w[(oc >> 3) * 576 + (kg >> 3) * 8 + ((oc - kg) & 7)];
        unsigned short h, l;
        bf16split(val, h, l);
        ((unsigned short*)(wfrag + okm * 2048))[lane * 8 + j] = h;
        ((unsigned short*)(wfrag + okm * 2048 + 1024))[lane * 8 + j] = l;
    }
}

// ---------------------------------------------------------------------------
// Kernel B: MFMA conv + tr + BN (fused via grid sync).
// grid (8 row-tiles, 64 batch) = 512 blocks, block 256 (4 waves), 2 blocks/CU.
// Block tile: 64 oc x 128 px. Wave (wmt,py): 32 oc x 64 px.
// LDS x2: [6 rows][34 cols][64 ch] bf16 hi+lo, granule-XOR swizzle:
//   byte(prec,r,c,ch) = prec*26112 + ((r*34+c)<<7) + (((ch>>3)^(c&7))<<4) + (ch&7)*2
// ---------------------------------------------------------------------------
__global__ __launch_bounds__(256, 2) void conv_kernel(const float* __restrict__ x,
                                                      const char* __restrict__ wfrag,
                                                      float* __restrict__ out,
                                                      float* __restrict__ stats,
                                                      const float* __restrict__ gamma,
                                                      const float* __restrict__ beta) {
    const int rt  = blockIdx.x;
    const int b   = blockIdx.y;
    const int tid = threadIdx.x;

    __shared__ __align__(16) char smem[SMEM_BYTES];

    // ---- zero halo cols (c=0 and c=33) ----
    if (tid < 192) {
        int prec = tid & 1;
        int g    = (tid >> 1) & 7;
        int rc   = tid >> 4;             // 0..11
        int r    = rc >> 1;
        int c    = (rc & 1) ? 33 : 0;
        *(uint4*)(smem + prec * X2_LO + ((r * 34 + c) << 7) + (g << 4)) = uint4{0, 0, 0, 0};
    }

    // ---- stage x^2 (hi/lo) ----
    {
        const int co  = tid & 7;          // col quad
        const int chp = tid >> 3;         // channel pair
        const float* xb = x + (size_t)(b * 64 + 2 * chp) * 1024;
#pragma unroll
        for (int rr = 0; rr < 6; ++rr) {
            int gr = rt * 4 - 1 + rr;
            float4 a0 = {0.f, 0.f, 0.f, 0.f}, a1 = {0.f, 0.f, 0.f, 0.f};
            if (gr >= 0 && gr < 32) {
                const float* rp = xb + gr * 32 + co * 4;
                a0 = *(const float4*)rp;
                a1 = *(const float4*)(rp + 1024);
            }
            float s0[4] = {a0.x * a0.x, a0.y * a0.y, a0.z * a0.z, a0.w * a0.w};
            float s1[4] = {a1.x * a1.x, a1.y * a1.y, a1.z * a1.z, a1.w * a1.w};
#pragma unroll
            for (int i = 0; i < 4; ++i) {
                unsigned short h0, l0, h1, l1;
                bf16split(s0[i], h0, l0);
                bf16split(s1[i], h1, l1);
                int c    = 1 + co * 4 + i;
                int base = ((rr * 34 + c) << 7) + ((((2 * chp) >> 3) ^ (c & 7)) << 4)
                         + ((chp & 3) << 2);
                *(unsigned*)(smem + base)         = (unsigned)h0 | ((unsigned)h1 << 16);
                *(unsigned*)(smem + X2_LO + base) = (unsigned)l0 | ((unsigned)l1 << 16);
            }
        }
    }
    __syncthreads();

    // ---- K loop: 9 taps (unroll 1) x 4 ksteps (full), 3-precision MFMA ----
    const int lane = tid & 63;
    const int wv   = tid >> 6;
    const int wmt  = wv & 1;             // oc half
    const int py   = wv >> 1;            // px row pair
    const int col  = lane & 31;
    const int hs   = lane >> 5;

    f32x16 acc0, acc1;
#pragma unroll
    for (int i = 0; i < 16; ++i) { acc0[i] = 0.f; acc1[i] = 0.f; }

    const char* wbase = wfrag + wmt * 2048 + (size_t)lane * 16;

#pragma unroll 1
    for (int di = 0; di < 3; ++di) {
#pragma unroll 1
        for (int dj = 0; dj < 3; ++dj) {
            const int off = di * 3 + dj;
            const int c   = col + dj;
            const int c7  = c & 7;
            const char* sb0 = smem + (((py * 2 + di) * 34 + c) << 7);
            const char* wp  = wbase + off * 16384;
#pragma unroll
            for (int ks = 0; ks < 4; ++ks) {
                const int g = ((ks * 2 + hs) ^ c7) << 4;
                bf16x8 bh0 = *(const bf16x8*)(sb0 + g);
                bf16x8 bl0 = *(const bf16x8*)(sb0 + X2_LO + g);
                bf16x8 bh1 = *(const bf16x8*)(sb0 + (34 << 7) + g);
                bf16x8 bl1 = *(const bf16x8*)(sb0 + X2_LO + (34 << 7) + g);
                bf16x8 ah  = *(const bf16x8*)(wp + ks * 4096);
                bf16x8 al  = *(const bf16x8*)(wp + ks * 4096 + 1024);
                acc0 = __builtin_amdgcn_mfma_f32_32x32x16_bf16(ah, bh0, acc0, 0, 0, 0);
                acc1 = __builtin_amdgcn_mfma_f32_32x32x16_bf16(ah, bh1, acc1, 0, 0, 0);
                acc0 = __builtin_amdgcn_mfma_f32_32x32x16_bf16(ah, bl0, acc0, 0, 0, 0);
                acc1 = __builtin_amdgcn_mfma_f32_32x32x16_bf16(ah, bl1, acc1, 0, 0, 0);
                acc0 = __builtin_amdgcn_mfma_f32_32x32x16_bf16(al, bh0, acc0, 0, 0, 0);
                acc1 = __builtin_amdgcn_mfma_f32_32x32x16_bf16(al, bh1, acc1, 0, 0, 0);
            }
        }
    }

    // ---- tr transform (values stay in registers) ----
#pragma unroll
    for (int r = 0; r < 16; ++r) {
        float c0 = __cosf(acc0[r]);
        float c1 = __cosf(acc1[r]);
        acc0[r] = fmaf(TR_C2, c0, TR_C1) / fmaf(TR_C2, c0, TR_C3);
        acc1[r] = fmaf(TR_C2, c1, TR_C1) / fmaf(TR_C2, c1, TR_C3);
    }

    // ---- per-channel partial sums (block reduce -> device atomics) ----
    float* red1 = (float*)smem;            // [64][66]
    float* red2 = red1 + 64 * 66;          // [64][66]
    float* ssc  = red2 + 64 * 66;          // [64]
    float* ssh  = ssc + 64;                // [64]

    __syncthreads();                        // x2 reads done, smem reusable
#pragma unroll
    for (int r = 0; r < 16; ++r) {
        int ocl  = (r & 3) + 8 * (r >> 2) + 4 * hs;
        float t0 = acc0[r], t1 = acc1[r];
        int ri = (wmt * 32 + ocl) * 66 + py * 32 + col;
        red1[ri] = t0 + t1;
        red2[ri] = t0 * t0 + t1 * t1;
    }
    __syncthreads();
    {
        const int ocr = tid & 63, q = tid >> 6;
        float s1 = 0.f, s2 = 0.f;
#pragma unroll
        for (int i = 0; i < 16; ++i) {
            s1 += red1[ocr * 66 + q * 16 + i];
            s2 += red2[ocr * 66 + q * 16 + i];
        }
        __syncthreads();
        red1[tid] = s1;
        red2[tid] = s2;
        __syncthreads();
        if (tid < 64) {
            float a1 = red1[tid] + red1[tid + 64] + red1[tid + 128] + red1[tid + 192];
            float a2 = red2[tid] + red2[tid + 64] + red2[tid + 128] + red2[tid + 192];
            atomicAdd(&stats[tid], a1);
            atomicAdd(&stats[64 + tid], a2);
        }
    }

    // ---- grid-wide sync, then finalize BN in-register and store once ----
    cg::this_grid().sync();

    if (tid < 64) {
        float s1 = __hip_atomic_load(&stats[tid], __ATOMIC_RELAXED, __HIP_MEMORY_SCOPE_AGENT);
        float s2 = __hip_atomic_load(&stats[64 + tid], __ATOMIC_RELAXED, __HIP_MEMORY_SCOPE_AGENT);
        const float invN = 1.0f / (float)NPIX;
        float mean = s1 * invN;
        float var  = s2 * invN - mean * mean;
        float sc   = gamma[tid] * rsqrtf(var + BN_EPS);
        ssc[tid] = sc;
        ssh[tid] = beta[tid] - mean * sc;
    }
    __syncthreads();

    const size_t outbase = ((size_t)b * 64 + wmt * 32) * 1024 + rt * 128;
#pragma unroll
    for (int r = 0; r < 16; ++r) {
        int ocl  = (r & 3) + 8 * (r >> 2) + 4 * hs;
        float sc = ssc[wmt * 32 + ocl];
        float sh = ssh[wmt * 32 + ocl];
        float y0 = fminf(1.0f, fmaxf(-1.0f, fmaf(acc0[r], sc, sh)));
        float y1 = fminf(1.0f, fmaxf(-1.0f, fmaf(acc1[r], sc, sh)));
        size_t o = outbase + (size_t)ocl * 1024 + py * 64 + col;
        out[o]      = y0;
        out[o + 32] = y1;
    }
}

// ---------------------------------------------------------------------------
extern "C" void kernel_launch(void* const* d_in, const int* in_sizes, int n_in,
                              void* d_out, int out_size, void* d_ws, size_t ws_size,
                              hipStream_t stream) {
    const float* x     = (const float*)d_in[0];
    const float* w     = (const float*)d_in[1];
    const float* gamma = (const float*)d_in[2];
    const float* beta  = (const float*)d_in[3];
    float* out = (float*)d_out;

    char*  wfrag = (char*)d_ws;                       // 147456 B
    float* stats = (float*)((char*)d_ws + 147456);    // 128 floats

    hipLaunchKernelGGL(prep_kernel, dim3(144), dim3(256), 0, stream, w, wfrag, stats);

    void* cargs[] = { (void*)&x, (void*)&wfrag, (void*)&out,
                      (void*)&stats, (void*)&gamma, (void*)&beta };
    hipLaunchCooperativeKernel((const void*)conv_kernel, dim3(8, 64), dim3(256),
                               cargs, 0, stream);
}

// Round 5
// 48.969 us; speedup vs baseline: 1.6174x; 1.6174x over previous
//
#include <hip/hip_runtime.h>
#include <hip/hip_cooperative_groups.h>

namespace cg = cooperative_groups;

// ---------------------------------------------------------------------------
// ConvBlock: y = clip(BN(tr(conv3x3(x^2, Wconv))), -1, 1)
// Wconv[oc][c][di][dj] = weight[oc>>3][(c*9+3di+dj)>>3][(oc-(c*9+3di+dj))&7]
// GEMM: A = Wconv (M=64 oc), B = im2col(x^2) (N=65536 px), K=576.
// bf16 MFMA 32x32x16, 3-pass hi/lo split.
// Round 5: 512-thr blocks (8 waves: wmt x kh x py), 2 blocks/CU (proven
// cooperative residency), full unroll, B-frag row reuse across di.
// Fallback (occupancy query + launch-error check): non-fused + stats + norm.
// ---------------------------------------------------------------------------

#define A_MORR 0.8578f
#define R_MORR 0.8578f
#define TR_C1 (A_MORR * A_MORR + R_MORR * R_MORR)
#define TR_C2 (-2.0f * A_MORR * R_MORR)
#define TR_C3 (1.0f + (A_MORR * R_MORR) * (A_MORR * R_MORR))
#define BN_EPS 1e-5f

#define NPIX 65536
#define X2_LO 26112          // 6*34*128: lo plane offset
#define SMEM_BYTES 52224

typedef __attribute__((ext_vector_type(8))) short bf16x8;
typedef __attribute__((ext_vector_type(16))) float f32x16;

__device__ __forceinline__ void bf16split(float s, unsigned short& h, unsigned short& l) {
    union { float f; unsigned u; } cv; cv.f = s;
    unsigned r = (cv.u + 0x7fffu + ((cv.u >> 16) & 1u)) & 0xffff0000u;
    h = (unsigned short)(r >> 16);
    union { unsigned u; float f; } hv; hv.u = r;
    float lo = s - hv.f;
    cv.f = lo;
    unsigned r2 = cv.u + 0x7fffu + ((cv.u >> 16) & 1u);
    l = (unsigned short)(r2 >> 16);
}

// ---------------------------------------------------------------------------
// Kernel A: fragment-ready bf16 hi/lo weights + zero stats.
// wfrag[off*8 + ks*2 + mt][prec][lane][8ch] : 72 * 2048 B
// ---------------------------------------------------------------------------
__global__ __launch_bounds__(256) void prep_kernel(const float* __restrict__ w,
                                                   char* __restrict__ wfrag,
                                                   float* __restrict__ stats) {
    int gtid = blockIdx.x * 256 + threadIdx.x;
    if (gtid < 128) stats[gtid] = 0.0f;
    if (gtid < 36864) {
        int j    = gtid & 7;
        int lane = (gtid >> 3) & 63;
        int okm  = gtid >> 9;
        int mt   = okm & 1;
        int ks   = (okm >> 1) & 3;
        int off  = okm >> 3;
        int oc   = mt * 32 + (lane & 31);
        int c    = ks * 16 + (lane >> 5) * 8 + j;
        int kg   = c * 9 + off;
        float val = w[(oc >> 3) * 576 + (kg >> 3) * 8 + ((oc - kg) & 7)];
        unsigned short h, l;
        bf16split(val, h, l);
        ((unsigned short*)(wfrag + okm * 2048))[lane * 8 + j] = h;
        ((unsigned short*)(wfrag + okm * 2048 + 1024))[lane * 8 + j] = l;
    }
}

// ---------------------------------------------------------------------------
// Kernel B: MFMA conv + tr (+ BN when FUSED).
// grid (8,64) = 512 blocks, block 512 (8 waves), 2 blocks/CU = 16 waves/CU.
// Block tile: 64 oc x 128 px (4 image rows rt*4..rt*4+3).
// Wave (wmt, kh, py): 32 oc x 64 px (rows rt*4+py*2, +1), K-half kh.
// LDS x2: [6 rows][34 cols][64 ch] bf16 hi+lo, granule-XOR swizzle:
//   byte(prec,r,c,ch) = prec*26112 + ((r*34+c)<<7) + (((ch>>3)^(c&7))<<4) + (ch&7)*2
// ---------------------------------------------------------------------------
template <int FUSED>
__global__ __launch_bounds__(512, 4) void conv_kernel(const float* __restrict__ x,
                                                      const char* __restrict__ wfrag,
                                                      float* __restrict__ out,
                                                      float* __restrict__ stats,
                                                      const float* __restrict__ gamma,
                                                      const float* __restrict__ beta) {
    const int rt  = blockIdx.x;          // 4-row tile 0..7
    const int b   = blockIdx.y;
    const int tid = threadIdx.x;

    __shared__ __align__(16) char smem[SMEM_BYTES];

    // ---- zero halo cols (c=0, c=33): 6 rows x 2 cols x 8 granules x 2 prec ----
    if (tid < 192) {
        int prec = tid & 1;
        int g    = (tid >> 1) & 7;
        int rc   = tid >> 4;             // 0..11
        int r    = rc >> 1;
        int c    = (rc & 1) ? 33 : 0;
        *(uint4*)(smem + prec * X2_LO + ((r * 34 + c) << 7) + (g << 4)) = uint4{0, 0, 0, 0};
    }

    // ---- stage x^2 (hi/lo), rows rt*4-1 .. rt*4+4 ----
    {
        const int rh  = tid & 1;          // row half (3 rows each)
        const int co  = (tid >> 1) & 7;   // col quad
        const int chp = tid >> 4;         // channel pair 0..31
        const float* xb = x + (size_t)(b * 64 + 2 * chp) * 1024;
#pragma unroll
        for (int r3 = 0; r3 < 3; ++r3) {
            int rr = rh * 3 + r3;
            int gr = rt * 4 - 1 + rr;
            float4 a0 = {0.f, 0.f, 0.f, 0.f}, a1 = {0.f, 0.f, 0.f, 0.f};
            if (gr >= 0 && gr < 32) {
                const float* rp = xb + gr * 32 + co * 4;
                a0 = *(const float4*)rp;
                a1 = *(const float4*)(rp + 1024);
            }
            float s0[4] = {a0.x * a0.x, a0.y * a0.y, a0.z * a0.z, a0.w * a0.w};
            float s1[4] = {a1.x * a1.x, a1.y * a1.y, a1.z * a1.z, a1.w * a1.w};
#pragma unroll
            for (int i = 0; i < 4; ++i) {
                unsigned short h0, l0, h1, l1;
                bf16split(s0[i], h0, l0);
                bf16split(s1[i], h1, l1);
                int c    = 1 + co * 4 + i;
                int base = ((rr * 34 + c) << 7) + (((chp >> 2) ^ (c & 7)) << 4)
                         + ((chp & 3) << 2);
                *(unsigned*)(smem + base)         = (unsigned)h0 | ((unsigned)h1 << 16);
                *(unsigned*)(smem + X2_LO + base) = (unsigned)l0 | ((unsigned)l1 << 16);
            }
        }
    }
    __syncthreads();

    // ---- K loop: dj x ks(K-half) with B-frag rows hoisted, reused across di ----
    const int lane = tid & 63;
    const int wv   = tid >> 6;
    const int wmt  = wv & 1;             // oc half
    const int kh   = (wv >> 1) & 1;      // K half
    const int py   = wv >> 2;            // row pair
    const int col  = lane & 31;
    const int hs   = lane >> 5;
    const int rowb = py * 2;

    f32x16 acc0, acc1;                   // rows rt*4+py*2, +1
#pragma unroll
    for (int i = 0; i < 16; ++i) { acc0[i] = 0.f; acc1[i] = 0.f; }

    const char* wbase = wfrag + wmt * 2048 + (size_t)lane * 16;

#pragma unroll
    for (int dj = 0; dj < 3; ++dj) {
        const int c  = col + dj;
        const int c7 = c & 7;
#pragma unroll
        for (int ksi = 0; ksi < 2; ++ksi) {
            const int ks = kh * 2 + ksi;
            const int g  = ((ks * 2 + hs) ^ c7) << 4;
            bf16x8 bh[4], bl[4];
#pragma unroll
            for (int rr = 0; rr < 4; ++rr) {
                const char* sp = smem + (((rowb + rr) * 34 + c) << 7) + g;
                bh[rr] = *(const bf16x8*)sp;
                bl[rr] = *(const bf16x8*)(sp + X2_LO);
            }
#pragma unroll
            for (int di = 0; di < 3; ++di) {
                const char* wp = wbase + (di * 3 + dj) * 16384 + ks * 4096;
                bf16x8 ah = *(const bf16x8*)wp;
                bf16x8 al = *(const bf16x8*)(wp + 1024);
                acc0 = __builtin_amdgcn_mfma_f32_32x32x16_bf16(ah, bh[di],     acc0, 0, 0, 0);
                acc1 = __builtin_amdgcn_mfma_f32_32x32x16_bf16(ah, bh[di + 1], acc1, 0, 0, 0);
                acc0 = __builtin_amdgcn_mfma_f32_32x32x16_bf16(ah, bl[di],     acc0, 0, 0, 0);
                acc1 = __builtin_amdgcn_mfma_f32_32x32x16_bf16(ah, bl[di + 1], acc1, 0, 0, 0);
                acc0 = __builtin_amdgcn_mfma_f32_32x32x16_bf16(al, bh[di],     acc0, 0, 0, 0);
                acc1 = __builtin_amdgcn_mfma_f32_32x32x16_bf16(al, bh[di + 1], acc1, 0, 0, 0);
            }
        }
    }

    // ---- merge K-halves through LDS, tr on kh==0 ----
    float* mergef = (float*)smem;                 // [8 slots][16 r][64 lane]
    __syncthreads();                               // S1: K-loop LDS reads done
    {
        const int slot = (wmt * 2 + py) * 2;
        if (kh == 1) {
#pragma unroll
            for (int r = 0; r < 16; ++r) {
                mergef[((slot + 0) * 16 + r) * 64 + lane] = acc0[r];
                mergef[((slot + 1) * 16 + r) * 64 + lane] = acc1[r];
            }
        }
        __syncthreads();                           // S2
        if (kh == 0) {
#pragma unroll
            for (int r = 0; r < 16; ++r) {
                float p0 = acc0[r] + mergef[((slot + 0) * 16 + r) * 64 + lane];
                float p1 = acc1[r] + mergef[((slot + 1) * 16 + r) * 64 + lane];
                float c0 = __cosf(p0);
                float c1 = __cosf(p1);
                acc0[r] = fmaf(TR_C2, c0, TR_C1) / fmaf(TR_C2, c0, TR_C3);
                acc1[r] = fmaf(TR_C2, c1, TR_C1) / fmaf(TR_C2, c1, TR_C3);
            }
        }
    }
    __syncthreads();                               // S3: merge reads done

    // ---- per-channel partial sums ----
    float* red1 = mergef;                          // [64][66]
    float* red2 = red1 + 64 * 66;                  // [64][66]
    if (kh == 0) {
#pragma unroll
        for (int r = 0; r < 16; ++r) {
            int ocl  = (r & 3) + 8 * (r >> 2) + 4 * hs;
            float t0 = acc0[r], t1 = acc1[r];
            int ri = (wmt * 32 + ocl) * 66 + py * 32 + col;
            red1[ri] = t0 + t1;
            red2[ri] = t0 * t0 + t1 * t1;
        }
    }
    __syncthreads();                               // S4
    if (tid < 64) {
        float s1 = 0.f, s2 = 0.f;
#pragma unroll
        for (int q = 0; q < 64; ++q) {
            s1 += red1[tid * 66 + q];
            s2 += red2[tid * 66 + q];
        }
        atomicAdd(&stats[tid], s1);
        atomicAdd(&stats[64 + tid], s2);
    }

    if constexpr (FUSED) {
        // ---- grid sync, finalize BN, store once ----
        cg::this_grid().sync();
        float* ssc = red2 + 64 * 66;               // 128 floats, fits in 52224B
        float* ssh = ssc + 64;
        if (tid < 64) {
            float s1 = __hip_atomic_load(&stats[tid], __ATOMIC_RELAXED, __HIP_MEMORY_SCOPE_AGENT);
            float s2 = __hip_atomic_load(&stats[64 + tid], __ATOMIC_RELAXED, __HIP_MEMORY_SCOPE_AGENT);
            const float invN = 1.0f / (float)NPIX;
            float mean = s1 * invN;
            float var  = s2 * invN - mean * mean;
            float sc   = gamma[tid] * rsqrtf(var + BN_EPS);
            ssc[tid] = sc;
            ssh[tid] = beta[tid] - mean * sc;
        }
        __syncthreads();
        if (kh == 0) {
            const size_t outbase = ((size_t)b * 64 + wmt * 32) * 1024 + rt * 128;
#pragma unroll
            for (int r = 0; r < 16; ++r) {
                int ocl  = (r & 3) + 8 * (r >> 2) + 4 * hs;
                float sc = ssc[wmt * 32 + ocl];
                float sh = ssh[wmt * 32 + ocl];
                float y0 = fminf(1.0f, fmaxf(-1.0f, fmaf(acc0[r], sc, sh)));
                float y1 = fminf(1.0f, fmaxf(-1.0f, fmaf(acc1[r], sc, sh)));
                size_t o = outbase + (size_t)ocl * 1024 + py * 64 + col;
                out[o]      = y0;
                out[o + 32] = y1;
            }
        }
    } else {
        // ---- store raw tr; BN applied by separate kernels ----
        if (kh == 0) {
            const size_t outbase = ((size_t)b * 64 + wmt * 32) * 1024 + rt * 128;
#pragma unroll
            for (int r = 0; r < 16; ++r) {
                int ocl  = (r & 3) + 8 * (r >> 2) + 4 * hs;
                size_t o = outbase + (size_t)ocl * 1024 + py * 64 + col;
                out[o]      = acc0[r];
                out[o + 32] = acc1[r];
            }
        }
    }
}

// ---------------------------------------------------------------------------
// Fallback kernels (used only if cooperative launch can't fit)
// ---------------------------------------------------------------------------
__global__ __launch_bounds__(64) void stats_kernel(const float* __restrict__ stats,
                                                   const float* __restrict__ gamma,
                                                   const float* __restrict__ beta,
                                                   float* __restrict__ ss) {
    int oc = threadIdx.x;
    if (oc >= 64) return;
    const float invN = 1.0f / (float)NPIX;
    float mean = stats[oc] * invN;
    float var  = stats[64 + oc] * invN - mean * mean;
    float sc   = gamma[oc] * rsqrtf(var + BN_EPS);
    ss[oc]      = sc;
    ss[64 + oc] = beta[oc] - mean * sc;
}

__global__ __launch_bounds__(256) void norm_kernel(float* __restrict__ out,
                                                   const float* __restrict__ ss) {
    int i = blockIdx.x * 256 + threadIdx.x;
    float4 v = ((float4*)out)[i];
    int oc = (i >> 8) & 63;
    float sc = ss[oc];
    float sh = ss[64 + oc];
    v.x = fminf(1.0f, fmaxf(-1.0f, fmaf(v.x, sc, sh)));
    v.y = fminf(1.0f, fmaxf(-1.0f, fmaf(v.y, sc, sh)));
    v.z = fminf(1.0f, fmaxf(-1.0f, fmaf(v.z, sc, sh)));
    v.w = fminf(1.0f, fmaxf(-1.0f, fmaf(v.w, sc, sh)));
    ((float4*)out)[i] = v;
}

// ---------------------------------------------------------------------------
extern "C" void kernel_launch(void* const* d_in, const int* in_sizes, int n_in,
                              void* d_out, int out_size, void* d_ws, size_t ws_size,
                              hipStream_t stream) {
    const float* x     = (const float*)d_in[0];
    const float* w     = (const float*)d_in[1];
    const float* gamma = (const float*)d_in[2];
    const float* beta  = (const float*)d_in[3];
    float* out = (float*)d_out;

    char*  wfrag = (char*)d_ws;                       // 147456 B
    float* stats = (float*)((char*)d_ws + 147456);    // 128 floats
    float* ss    = stats + 128;                       // 128 floats

    hipLaunchKernelGGL(prep_kernel, dim3(144), dim3(256), 0, stream, w, wfrag, stats);

    // deterministic decision: fused cooperative path iff 2 blocks/CU fit
    int maxb = 0;
    hipError_t qe = hipOccupancyMaxActiveBlocksPerMultiprocessor(
        &maxb, reinterpret_cast<const void*>(&conv_kernel<1>), 512, 0);
    bool fused = (qe == hipSuccess) && (maxb >= 2);

    if (fused) {
        void* cargs[] = { (void*)&x, (void*)&wfrag, (void*)&out,
                          (void*)&stats, (void*)&gamma, (void*)&beta };
        hipError_t le = hipLaunchCooperativeKernel(
            reinterpret_cast<const void*>(&conv_kernel<1>),
            dim3(8, 64), dim3(512), cargs, 0, stream);
        if (le != hipSuccess) fused = false;
    }
    if (!fused) {
        hipLaunchKernelGGL(conv_kernel<0>, dim3(8, 64), dim3(512), 0, stream,
                           x, wfrag, out, stats, gamma, beta);
        hipLaunchKernelGGL(stats_kernel, dim3(1), dim3(64), 0, stream, stats, gamma, beta, ss);
        hipLaunchKernelGGL(norm_kernel, dim3(4096), dim3(256), 0, stream, out, ss);
    }
}

// Round 6
// 42.001 us; speedup vs baseline: 1.8857x; 1.1659x over previous
//
#include <hip/hip_runtime.h>

// ---------------------------------------------------------------------------
// ConvBlock: y = clip(BN(tr(conv3x3(x^2, Wconv))), -1, 1)
// Wconv[oc][c][di][dj] = weight[oc>>3][(c*9+3di+dj)>>3][(oc-(c*9+3di+dj))&7]
// GEMM: A = Wconv (M=64 oc), B = im2col(x^2) (N=65536 px), K=576.
// bf16 MFMA 32x32x16, 3-pass hi/lo split.
// Round 6: NO global atomics (per-block partial slots), no cooperative sync,
// launch_bounds(512,2) for a 128-VGPR budget. 4-kernel pipeline.
// ---------------------------------------------------------------------------

#define A_MORR 0.8578f
#define R_MORR 0.8578f
#define TR_C1 (A_MORR * A_MORR + R_MORR * R_MORR)
#define TR_C2 (-2.0f * A_MORR * R_MORR)
#define TR_C3 (1.0f + (A_MORR * R_MORR) * (A_MORR * R_MORR))
#define BN_EPS 1e-5f

#define NPIX 65536
#define X2_LO 26112          // 6*34*128: lo plane offset
#define SMEM_BYTES 52224
#define NBLK 512             // conv grid size

typedef __attribute__((ext_vector_type(8))) short bf16x8;
typedef __attribute__((ext_vector_type(16))) float f32x16;

__device__ __forceinline__ void bf16split(float s, unsigned short& h, unsigned short& l) {
    union { float f; unsigned u; } cv; cv.f = s;
    unsigned r = (cv.u + 0x7fffu + ((cv.u >> 16) & 1u)) & 0xffff0000u;
    h = (unsigned short)(r >> 16);
    union { unsigned u; float f; } hv; hv.u = r;
    float lo = s - hv.f;
    cv.f = lo;
    unsigned r2 = cv.u + 0x7fffu + ((cv.u >> 16) & 1u);
    l = (unsigned short)(r2 >> 16);
}

// ---------------------------------------------------------------------------
// Kernel A: fragment-ready bf16 hi/lo weights.
// wfrag[off*8 + ks*2 + mt][prec][lane][8ch] : 72 * 2048 B
// ---------------------------------------------------------------------------
__global__ __launch_bounds__(256) void prep_kernel(const float* __restrict__ w,
                                                   char* __restrict__ wfrag) {
    int gtid = blockIdx.x * 256 + threadIdx.x;
    if (gtid < 36864) {
        int j    = gtid & 7;
        int lane = (gtid >> 3) & 63;
        int okm  = gtid >> 9;
        int mt   = okm & 1;
        int ks   = (okm >> 1) & 3;
        int off  = okm >> 3;
        int oc   = mt * 32 + (lane & 31);
        int c    = ks * 16 + (lane >> 5) * 8 + j;
        int kg   = c * 9 + off;
        float val = w[(oc >> 3) * 576 + (kg >> 3) * 8 + ((oc - kg) & 7)];
        unsigned short h, l;
        bf16split(val, h, l);
        ((unsigned short*)(wfrag + okm * 2048))[lane * 8 + j] = h;
        ((unsigned short*)(wfrag + okm * 2048 + 1024))[lane * 8 + j] = l;
    }
}

// ---------------------------------------------------------------------------
// Kernel B: MFMA conv + tr; per-block BN partials (no atomics).
// grid (8,64) = 512 blocks, block 512 (8 waves: wmt x kh x py), 2 blocks/CU.
// Block tile: 64 oc x 128 px (4 image rows rt*4..rt*4+3).
// LDS x2: [6 rows][34 cols][64 ch] bf16 hi+lo, granule-XOR swizzle:
//   byte(prec,r,c,ch) = prec*26112 + ((r*34+c)<<7) + (((ch>>3)^(c&7))<<4) + (ch&7)*2
// partials layout: [128 stat][512 block]
// ---------------------------------------------------------------------------
__global__ __launch_bounds__(512, 2) void conv_kernel(const float* __restrict__ x,
                                                      const char* __restrict__ wfrag,
                                                      float* __restrict__ out,
                                                      float* __restrict__ partials) {
    const int rt  = blockIdx.x;          // 4-row tile 0..7
    const int b   = blockIdx.y;
    const int bid = b * 8 + rt;          // 0..511
    const int tid = threadIdx.x;

    __shared__ __align__(16) char smem[SMEM_BYTES];

    // ---- zero halo cols (c=0, c=33) ----
    if (tid < 192) {
        int prec = tid & 1;
        int g    = (tid >> 1) & 7;
        int rc   = tid >> 4;             // 0..11
        int r    = rc >> 1;
        int c    = (rc & 1) ? 33 : 0;
        *(uint4*)(smem + prec * X2_LO + ((r * 34 + c) << 7) + (g << 4)) = uint4{0, 0, 0, 0};
    }

    // ---- stage x^2 (hi/lo), rows rt*4-1 .. rt*4+4 ----
    {
        const int rh  = tid & 1;
        const int co  = (tid >> 1) & 7;
        const int chp = tid >> 4;
        const float* xb = x + (size_t)(b * 64 + 2 * chp) * 1024;
#pragma unroll
        for (int r3 = 0; r3 < 3; ++r3) {
            int rr = rh * 3 + r3;
            int gr = rt * 4 - 1 + rr;
            float4 a0 = {0.f, 0.f, 0.f, 0.f}, a1 = {0.f, 0.f, 0.f, 0.f};
            if (gr >= 0 && gr < 32) {
                const float* rp = xb + gr * 32 + co * 4;
                a0 = *(const float4*)rp;
                a1 = *(const float4*)(rp + 1024);
            }
            float s0[4] = {a0.x * a0.x, a0.y * a0.y, a0.z * a0.z, a0.w * a0.w};
            float s1[4] = {a1.x * a1.x, a1.y * a1.y, a1.z * a1.z, a1.w * a1.w};
#pragma unroll
            for (int i = 0; i < 4; ++i) {
                unsigned short h0, l0, h1, l1;
                bf16split(s0[i], h0, l0);
                bf16split(s1[i], h1, l1);
                int c    = 1 + co * 4 + i;
                int base = ((rr * 34 + c) << 7) + (((chp >> 2) ^ (c & 7)) << 4)
                         + ((chp & 3) << 2);
                *(unsigned*)(smem + base)         = (unsigned)h0 | ((unsigned)h1 << 16);
                *(unsigned*)(smem + X2_LO + base) = (unsigned)l0 | ((unsigned)l1 << 16);
            }
        }
    }
    __syncthreads();

    // ---- K loop: dj x ks(K-half), B-frag rows hoisted, reused across di ----
    const int lane = tid & 63;
    const int wv   = tid >> 6;
    const int wmt  = wv & 1;             // oc half
    const int kh   = (wv >> 1) & 1;      // K half
    const int py   = wv >> 2;            // row pair
    const int col  = lane & 31;
    const int hs   = lane >> 5;
    const int rowb = py * 2;

    f32x16 acc0, acc1;
#pragma unroll
    for (int i = 0; i < 16; ++i) { acc0[i] = 0.f; acc1[i] = 0.f; }

    const char* wbase = wfrag + wmt * 2048 + (size_t)lane * 16;

#pragma unroll
    for (int dj = 0; dj < 3; ++dj) {
        const int c  = col + dj;
        const int c7 = c & 7;
#pragma unroll
        for (int ksi = 0; ksi < 2; ++ksi) {
            const int ks = kh * 2 + ksi;
            const int g  = ((ks * 2 + hs) ^ c7) << 4;
            bf16x8 bh[4], bl[4];
#pragma unroll
            for (int rr = 0; rr < 4; ++rr) {
                const char* sp = smem + (((rowb + rr) * 34 + c) << 7) + g;
                bh[rr] = *(const bf16x8*)sp;
                bl[rr] = *(const bf16x8*)(sp + X2_LO);
            }
#pragma unroll
            for (int di = 0; di < 3; ++di) {
                const char* wp = wbase + (di * 3 + dj) * 16384 + ks * 4096;
                bf16x8 ah = *(const bf16x8*)wp;
                bf16x8 al = *(const bf16x8*)(wp + 1024);
                acc0 = __builtin_amdgcn_mfma_f32_32x32x16_bf16(ah, bh[di],     acc0, 0, 0, 0);
                acc1 = __builtin_amdgcn_mfma_f32_32x32x16_bf16(ah, bh[di + 1], acc1, 0, 0, 0);
                acc0 = __builtin_amdgcn_mfma_f32_32x32x16_bf16(ah, bl[di],     acc0, 0, 0, 0);
                acc1 = __builtin_amdgcn_mfma_f32_32x32x16_bf16(ah, bl[di + 1], acc1, 0, 0, 0);
                acc0 = __builtin_amdgcn_mfma_f32_32x32x16_bf16(al, bh[di],     acc0, 0, 0, 0);
                acc1 = __builtin_amdgcn_mfma_f32_32x32x16_bf16(al, bh[di + 1], acc1, 0, 0, 0);
            }
        }
    }

    // ---- merge K-halves through LDS, tr on kh==0 ----
    float* mergef = (float*)smem;                 // 8 slots x 16 r x 64 lane
    __syncthreads();                               // S1
    {
        const int slot = (wmt * 2 + py) * 2;
        if (kh == 1) {
#pragma unroll
            for (int r = 0; r < 16; ++r) {
                mergef[((slot + 0) * 16 + r) * 64 + lane] = acc0[r];
                mergef[((slot + 1) * 16 + r) * 64 + lane] = acc1[r];
            }
        }
        __syncthreads();                           // S2
        if (kh == 0) {
#pragma unroll
            for (int r = 0; r < 16; ++r) {
                float p0 = acc0[r] + mergef[((slot + 0) * 16 + r) * 64 + lane];
                float p1 = acc1[r] + mergef[((slot + 1) * 16 + r) * 64 + lane];
                float c0 = __cosf(p0);
                float c1 = __cosf(p1);
                acc0[r] = fmaf(TR_C2, c0, TR_C1) / fmaf(TR_C2, c0, TR_C3);
                acc1[r] = fmaf(TR_C2, c1, TR_C1) / fmaf(TR_C2, c1, TR_C3);
            }
        }
    }
    __syncthreads();                               // S3

    // ---- per-channel partial sums -> per-block slot (NO atomics) ----
    float* red1 = mergef;                          // [64][66]
    float* red2 = red1 + 64 * 66;                  // [64][66]
    if (kh == 0) {
#pragma unroll
        for (int r = 0; r < 16; ++r) {
            int ocl  = (r & 3) + 8 * (r >> 2) + 4 * hs;
            float t0 = acc0[r], t1 = acc1[r];
            int ri = (wmt * 32 + ocl) * 66 + py * 32 + col;
            red1[ri] = t0 + t1;
            red2[ri] = t0 * t0 + t1 * t1;
        }
    }
    __syncthreads();                               // S4
    if (tid < 64) {
        float s1 = 0.f, s2 = 0.f;
#pragma unroll
        for (int q = 0; q < 64; ++q) {
            s1 += red1[tid * 66 + q];
            s2 += red2[tid * 66 + q];
        }
        partials[(size_t)tid * NBLK + bid]        = s1;
        partials[(size_t)(64 + tid) * NBLK + bid] = s2;
    }

    // ---- store raw tr (BN applied by norm kernel) ----
    if (kh == 0) {
        const size_t outbase = ((size_t)b * 64 + wmt * 32) * 1024 + rt * 128;
#pragma unroll
        for (int r = 0; r < 16; ++r) {
            int ocl  = (r & 3) + 8 * (r >> 2) + 4 * hs;
            size_t o = outbase + (size_t)ocl * 1024 + py * 64 + col;
            out[o]      = acc0[r];
            out[o + 32] = acc1[r];
        }
    }
}

// ---------------------------------------------------------------------------
// Kernel C: reduce per-block partials -> BN scale/shift. grid 64, block 512.
// ---------------------------------------------------------------------------
__global__ __launch_bounds__(512) void stats_kernel(const float* __restrict__ partials,
                                                    const float* __restrict__ gamma,
                                                    const float* __restrict__ beta,
                                                    float* __restrict__ ss) {
    const int c   = blockIdx.x;          // channel 0..63
    const int tid = threadIdx.x;
    __shared__ float r1[512], r2[512];
    r1[tid] = partials[(size_t)c * NBLK + tid];
    r2[tid] = partials[(size_t)(64 + c) * NBLK + tid];
    __syncthreads();
#pragma unroll
    for (int s = 256; s > 0; s >>= 1) {
        if (tid < s) {
            r1[tid] += r1[tid + s];
            r2[tid] += r2[tid + s];
        }
        __syncthreads();
    }
    if (tid == 0) {
        const float invN = 1.0f / (float)NPIX;
        float mean = r1[0] * invN;
        float var  = r2[0] * invN - mean * mean;
        float sc   = gamma[c] * rsqrtf(var + BN_EPS);
        ss[c]      = sc;
        ss[64 + c] = beta[c] - mean * sc;
    }
}

// ---------------------------------------------------------------------------
// Kernel D: in-place normalize + clip (float4)
// ---------------------------------------------------------------------------
__global__ __launch_bounds__(256) void norm_kernel(float* __restrict__ out,
                                                   const float* __restrict__ ss) {
    int i = blockIdx.x * 256 + threadIdx.x;
    float4 v = ((float4*)out)[i];
    int oc = (i >> 8) & 63;
    float sc = ss[oc];
    float sh = ss[64 + oc];
    v.x = fminf(1.0f, fmaxf(-1.0f, fmaf(v.x, sc, sh)));
    v.y = fminf(1.0f, fmaxf(-1.0f, fmaf(v.y, sc, sh)));
    v.z = fminf(1.0f, fmaxf(-1.0f, fmaf(v.z, sc, sh)));
    v.w = fminf(1.0f, fmaxf(-1.0f, fmaf(v.w, sc, sh)));
    ((float4*)out)[i] = v;
}

// ---------------------------------------------------------------------------
extern "C" void kernel_launch(void* const* d_in, const int* in_sizes, int n_in,
                              void* d_out, int out_size, void* d_ws, size_t ws_size,
                              hipStream_t stream) {
    const float* x     = (const float*)d_in[0];
    const float* w     = (const float*)d_in[1];
    const float* gamma = (const float*)d_in[2];
    const float* beta  = (const float*)d_in[3];
    float* out = (float*)d_out;

    char*  wfrag    = (char*)d_ws;                          // 147456 B
    float* partials = (float*)((char*)d_ws + 147456);       // 128*512 floats = 256 KB
    float* ss       = partials + 128 * NBLK;                // 128 floats

    hipLaunchKernelGGL(prep_kernel, dim3(144), dim3(256), 0, stream, w, wfrag);
    hipLaunchKernelGGL(conv_kernel, dim3(8, 64), dim3(512), 0, stream, x, wfrag, out, partials);
    hipLaunchKernelGGL(stats_kernel, dim3(64), dim3(512), 0, stream, partials, gamma, beta, ss);
    hipLaunchKernelGGL(norm_kernel, dim3(4096), dim3(256), 0, stream, out, ss);
}